// Round 5
// baseline (197.666 us; speedup 1.0000x reference)
//
#include <hip/hip_runtime.h>

typedef _Float16 half8  __attribute__((ext_vector_type(8)));
typedef _Float16 half4v __attribute__((ext_vector_type(4)));
typedef _Float16 half2v __attribute__((ext_vector_type(2)));
typedef float    floatx4 __attribute__((ext_vector_type(4)));
typedef float    float2v __attribute__((ext_vector_type(2)));

static constexpr float INVPI = 0.3183098861837907f;  // weights pre-scaled by 1/pi:
static constexpr float RLOG  = 3.82843f;             // MFMA emits 2*theta in revolutions

// Fused activation via double-angle (R16-verified): h = E + c2*(F + G*c2),
// c2 = cos(2theta), one cos per value.
// Tail in PACKED F16 (v_pk_fma_f16). The f32 v_pk_fma_f32 INLINE-ASM path
// FAILED numerically twice (R17/R18) -- do not retry it. (float2v via
// __builtin_elementwise_fma below is compiler-generated, exact per-lane IEEE,
// and safe whether or not it packs.)
static constexpr double RD = (double)RLOG;
static constexpr double AD = RD*RD/4.0 - RD*RD*RD/16.0;
static constexpr double BD = -RD*RD/4.0 + RD*RD*RD/8.0;
static constexpr double DD = -RD*RD*RD/16.0;
static constexpr float ACT_E = (float)(AD + BD/2.0 + DD/4.0);   //  0.955347
static constexpr float ACT_F = (float)((BD + DD)/2.0);          // -0.078584
static constexpr float ACT_G = (float)(DD/4.0);                 // -0.876763

// R23: R0-R4 all converge at 86-88us / VALUBusy ~64% invariant to occupancy &
// source schedule. Refit: 48 wave64 v_cos/tile x ~32cyc trans-pipe occupancy
// (quarter-rate unit) = 1536 of 1644 cyc/tile -> 93% TRANS saturation. The
// trans pipe IS the wall. Fix: cos(2pi*r) as even minimax poly (deg-6 in r^2,
// c6 economized, max err ~5e-6 << f16 ulp 4.9e-4) on the FULL-RATE VALU.
// rndne range-reduction is exact (|a2|<3). Expect VALUBusy -> 85%+, trans -> 0.
static constexpr double W2D = 39.478417604357434;    // (2*pi)^2
static constexpr float CC1 = (float)(-W2D/2.0);                          // -19.7392088
static constexpr float CC2 = (float)( W2D*W2D/24.0);                     //  64.9393940
static constexpr float CC3 = (float)(-W2D*W2D*W2D/720.0);                // -85.4568172
static constexpr float CC4 = (float)( W2D*W2D*W2D*W2D/40320.0);          //  60.2446398
static constexpr float CC5 = (float)(-W2D*W2D*W2D*W2D*W2D/3628800.0);    // -26.4263128
static constexpr float CC6 = (float)( W2D*W2D*W2D*W2D*W2D*W2D/479001600.0
                                      - 0.4105845);                      //   7.4929525 (minimax tweak)

__device__ __forceinline__ float cos2pi_s(float a) {   // cos(2*pi*a), |a| < 3
    float k = __builtin_rintf(a);                      // v_rndne_f32 (exact)
    float r = a - k;                                   // exact, r in [-0.5, 0.5]
    float u = r * r;                                   // u in [0, 0.25]
    float p = __builtin_fmaf(u, CC6, CC5);
    p = __builtin_fmaf(u, p, CC4);
    p = __builtin_fmaf(u, p, CC3);
    p = __builtin_fmaf(u, p, CC2);
    p = __builtin_fmaf(u, p, CC1);
    p = __builtin_fmaf(u, p, 1.0f);
    return p;
}

__device__ __forceinline__ float2v cos2pi_x2(float2v a) {  // packed-friendly pair form
    float2v k = {__builtin_rintf(a[0]), __builtin_rintf(a[1])};
    float2v r = a - k;
    float2v u = r * r;
    const float2v c6 = {CC6, CC6}, c5 = {CC5, CC5}, c4 = {CC4, CC4};
    const float2v c3 = {CC3, CC3}, c2 = {CC2, CC2}, c1 = {CC1, CC1};
    const float2v one = {1.0f, 1.0f};
    float2v p = __builtin_elementwise_fma(u, c6, c5);
    p = __builtin_elementwise_fma(u, p, c4);
    p = __builtin_elementwise_fma(u, p, c3);
    p = __builtin_elementwise_fma(u, p, c2);
    p = __builtin_elementwise_fma(u, p, c1);
    p = __builtin_elementwise_fma(u, p, one);
    return p;
}

__device__ __forceinline__ float act_rev(float a2) {   // a2 = 2*theta in revs (f32: final output)
    float c = cos2pi_s(a2);
    float t = __builtin_fmaf(ACT_G, c, ACT_F);
    return __builtin_fmaf(c, t, ACT_E);
}

// Two C-frags (tiles t, t+2) -> next-layer B-frag directly.
// Per 8 values: 4x packed poly (no trans!) + 4 cvt_pkrtz + 8 v_pk_fma_f16.
__device__ __forceinline__ half8 act8(floatx4 a, floatx4 b) {
    const half2v Gh = {(_Float16)ACT_G, (_Float16)ACT_G};
    const half2v Fh = {(_Float16)ACT_F, (_Float16)ACT_F};
    const half2v Eh = {(_Float16)ACT_E, (_Float16)ACT_E};
    float2v p0 = cos2pi_x2(float2v{a[0], a[1]});
    float2v p1 = cos2pi_x2(float2v{a[2], a[3]});
    float2v p2 = cos2pi_x2(float2v{b[0], b[1]});
    float2v p3 = cos2pi_x2(float2v{b[2], b[3]});
    half2v c0 = __builtin_bit_cast(half2v, __builtin_amdgcn_cvt_pkrtz(p0[0], p0[1]));
    half2v c1 = __builtin_bit_cast(half2v, __builtin_amdgcn_cvt_pkrtz(p1[0], p1[1]));
    half2v c2 = __builtin_bit_cast(half2v, __builtin_amdgcn_cvt_pkrtz(p2[0], p2[1]));
    half2v c3 = __builtin_bit_cast(half2v, __builtin_amdgcn_cvt_pkrtz(p3[0], p3[1]));
    half2v t0 = __builtin_elementwise_fma(c0, Gh, Fh);
    half2v t1 = __builtin_elementwise_fma(c1, Gh, Fh);
    half2v t2 = __builtin_elementwise_fma(c2, Gh, Fh);
    half2v t3 = __builtin_elementwise_fma(c3, Gh, Fh);
    half2v h0 = __builtin_elementwise_fma(c0, t0, Eh);
    half2v h1 = __builtin_elementwise_fma(c1, t1, Eh);
    half2v h2 = __builtin_elementwise_fma(c2, t2, Eh);
    half2v h3 = __builtin_elementwise_fma(c3, t3, Eh);
    half4v lo = __builtin_shufflevector(h0, h1, 0, 1, 2, 3);
    half4v hi = __builtin_shufflevector(h2, h3, 0, 1, 2, 3);
    return __builtin_shufflevector(lo, hi, 0, 1, 2, 3, 4, 5, 6, 7);
}

// Per-block LDS weight cache (R9/R11-proven; R12 showed biases-in-regs spill
// at the (512,8) 64-reg cap -- biases stay in LDS). R0/R11/R16 config exactly:
// 512-thread block, 8 waves/CU cap, grid 2048 (best-measured latency hiding).
struct SMem {
    half8   w2[8][64];   // [(t*2+c)][lane]
    half8   w3[8][64];
    floatx4 b2[4][64];   // [t][lane]
    floatx4 b3[4][64];
};

__global__ __launch_bounds__(512, 8) void mlp_fused(
    const float* __restrict__ x,
    const float* __restrict__ W1, const float* __restrict__ b1,
    const float* __restrict__ W2, const float* __restrict__ b2,
    const float* __restrict__ W3, const float* __restrict__ b3,
    const float* __restrict__ W4, const float* __restrict__ b4,
    float* __restrict__ out, int N)
{
    __shared__ SMem sm;
    const int lane = threadIdx.x & 63;
    const int wib  = threadIdx.x >> 6;   // 0..7
    const int m    = lane & 15;   // sample / C col / A row
    const int q    = lane >> 4;   // quad
    const float s  = INVPI;      // all layers: 1/pi scaling (double-angle form)
    const floatx4 zero4 = {0.0f, 0.0f, 0.0f, 0.0f};

    // ---- in-register persistent frags (small): L1 and L4 ----
    // L1 A-frag (tile t), lanes q==0: [w0h, w0h, w0l, w1h, w1h, w1l, b1h, b1l]
    half8 w1f[4];
    #pragma unroll
    for (int t = 0; t < 4; ++t) {
        half8 v = {};
        if (q == 0) {
            const int n = 16 * t + m;
            float w0 = W1[2*n] * s, w1 = W1[2*n+1] * s, bb = b1[n] * s;
            _Float16 w0h = (_Float16)w0; float w0l = w0 - (float)w0h;
            _Float16 w1h = (_Float16)w1; float w1l = w1 - (float)w1h;
            _Float16 bh  = (_Float16)bb; float bl  = bb - (float)bh;
            v[0] = w0h; v[1] = w0h; v[2] = (_Float16)w0l;
            v[3] = w1h; v[4] = w1h; v[5] = (_Float16)w1l;
            v[6] = bh;  v[7] = (_Float16)bl;
        }
        w1f[t] = v;
    }
    // L4 A-frag: only out-row m==0 real; sigma column permutation
    //   sigma: k-slot (c,q,j) -> neuron (j<4 ? 16c+4q+j : 16(c+2)+4q+j-4)
    half8 w4f[2] = {half8{}, half8{}};
    if (m == 0) {
        #pragma unroll
        for (int c = 0; c < 2; ++c)
            #pragma unroll
            for (int j = 0; j < 8; ++j) {
                int nu = (j < 4) ? (16 * c + 4 * q + j) : (16 * (c + 2) + 4 * q + j - 4);
                w4f[c][j] = (_Float16)(W4[nu] * s);
            }
    }
    floatx4 a4init = zero4;
    if (q == 0) a4init[0] = b4[0] * s;       // C row 0 = (q=0, r=0)

    // ---- wave-split LDS prep (sigma-permuted columns), one barrier ----
    if (wib == 0) {
        #pragma unroll
        for (int t = 0; t < 4; ++t) {
            const float* r2 = W2 + (16 * t + m) * 64;
            #pragma unroll
            for (int c = 0; c < 2; ++c) {
                floatx4 lo2 = *(const floatx4*)(r2 + 16 * c + 4 * q);
                floatx4 hi2 = *(const floatx4*)(r2 + 16 * (c + 2) + 4 * q);
                half8 v2;
                #pragma unroll
                for (int j = 0; j < 4; ++j) {
                    v2[j]     = (_Float16)(lo2[j] * s);
                    v2[4 + j] = (_Float16)(hi2[j] * s);
                }
                sm.w2[t * 2 + c][lane] = v2;
            }
        }
    } else if (wib == 1) {
        #pragma unroll
        for (int t = 0; t < 4; ++t) {
            const float* r3 = W3 + (16 * t + m) * 64;
            #pragma unroll
            for (int c = 0; c < 2; ++c) {
                floatx4 lo3 = *(const floatx4*)(r3 + 16 * c + 4 * q);
                floatx4 hi3 = *(const floatx4*)(r3 + 16 * (c + 2) + 4 * q);
                half8 v3;
                #pragma unroll
                for (int j = 0; j < 4; ++j) {
                    v3[j]     = (_Float16)(lo3[j] * s);
                    v3[4 + j] = (_Float16)(hi3[j] * s);
                }
                sm.w3[t * 2 + c][lane] = v3;
            }
        }
    } else if (wib == 2) {
        #pragma unroll
        for (int t = 0; t < 4; ++t) {
            sm.b2[t][lane] = *(const floatx4*)(b2 + 16 * t + 4 * q) * s;
            sm.b3[t][lane] = *(const floatx4*)(b3 + 16 * t + 4 * q) * s;
        }
    }
    __syncthreads();

    const int ntiles = N >> 4;
    const int nwaves = (gridDim.x * blockDim.x) >> 6;
    const int gwave  = (int)(blockIdx.x * blockDim.x + threadIdx.x) >> 6;
    const float2* __restrict__ x2 = (const float2*)x;

    int tile = gwave;
    float2 xv = x2[(tile << 4) + m];          // 1-ahead x prefetch
    while (tile < ntiles) {
        const int nt = tile + nwaves;
        float2 xnext;
        if (nt < ntiles) xnext = x2[(nt << 4) + m];

        // L1 B-frag (lanes q==0): [xh, xl, xh, yh, yl, yh, 1, 1]
        half8 xa = {};
        if (q == 0) {
            _Float16 xh = (_Float16)xv.x; float xl = xv.x - (float)xh;
            _Float16 yh = (_Float16)xv.y; float yl = xv.y - (float)yh;
            xa[0] = xh; xa[1] = (_Float16)xl; xa[2] = xh;
            xa[3] = yh; xa[4] = (_Float16)yl; xa[5] = yh;
            xa[6] = (_Float16)1.0f; xa[7] = (_Float16)1.0f;
        }

        // ---- layer 1 (in-register frags) ----
        floatx4 a0 = __builtin_amdgcn_mfma_f32_16x16x32_f16(w1f[0], xa, zero4, 0, 0, 0);
        floatx4 a1 = __builtin_amdgcn_mfma_f32_16x16x32_f16(w1f[1], xa, zero4, 0, 0, 0);
        floatx4 a2 = __builtin_amdgcn_mfma_f32_16x16x32_f16(w1f[2], xa, zero4, 0, 0, 0);
        floatx4 a3 = __builtin_amdgcn_mfma_f32_16x16x32_f16(w1f[3], xa, zero4, 0, 0, 0);
        half8 B0 = act8(a0, a2);
        half8 B1 = act8(a1, a3);

        // Opaque zero per layer: defeats LICM (else the LDS reads hoist back
        // into ~128 live regs and spill) AND staggers reads so peak staging
        // is one layer's worth.
        int z2 = 0; asm volatile("" : "+v"(z2));
        const int l2i = lane + z2;
        a0 = __builtin_amdgcn_mfma_f32_16x16x32_f16(sm.w2[0][l2i], B0, sm.b2[0][l2i], 0, 0, 0);
        a1 = __builtin_amdgcn_mfma_f32_16x16x32_f16(sm.w2[2][l2i], B0, sm.b2[1][l2i], 0, 0, 0);
        a2 = __builtin_amdgcn_mfma_f32_16x16x32_f16(sm.w2[4][l2i], B0, sm.b2[2][l2i], 0, 0, 0);
        a3 = __builtin_amdgcn_mfma_f32_16x16x32_f16(sm.w2[6][l2i], B0, sm.b2[3][l2i], 0, 0, 0);
        a0 = __builtin_amdgcn_mfma_f32_16x16x32_f16(sm.w2[1][l2i], B1, a0, 0, 0, 0);
        a1 = __builtin_amdgcn_mfma_f32_16x16x32_f16(sm.w2[3][l2i], B1, a1, 0, 0, 0);
        a2 = __builtin_amdgcn_mfma_f32_16x16x32_f16(sm.w2[5][l2i], B1, a2, 0, 0, 0);
        a3 = __builtin_amdgcn_mfma_f32_16x16x32_f16(sm.w2[7][l2i], B1, a3, 0, 0, 0);
        half8 C0 = act8(a0, a2);
        half8 C1 = act8(a1, a3);

        int z3 = 0; asm volatile("" : "+v"(z3));
        const int l3i = lane + z3;
        a0 = __builtin_amdgcn_mfma_f32_16x16x32_f16(sm.w3[0][l3i], C0, sm.b3[0][l3i], 0, 0, 0);
        a1 = __builtin_amdgcn_mfma_f32_16x16x32_f16(sm.w3[2][l3i], C0, sm.b3[1][l3i], 0, 0, 0);
        a2 = __builtin_amdgcn_mfma_f32_16x16x32_f16(sm.w3[4][l3i], C0, sm.b3[2][l3i], 0, 0, 0);
        a3 = __builtin_amdgcn_mfma_f32_16x16x32_f16(sm.w3[6][l3i], C0, sm.b3[3][l3i], 0, 0, 0);
        a0 = __builtin_amdgcn_mfma_f32_16x16x32_f16(sm.w3[1][l3i], C1, a0, 0, 0, 0);
        a1 = __builtin_amdgcn_mfma_f32_16x16x32_f16(sm.w3[3][l3i], C1, a1, 0, 0, 0);
        a2 = __builtin_amdgcn_mfma_f32_16x16x32_f16(sm.w3[5][l3i], C1, a2, 0, 0, 0);
        a3 = __builtin_amdgcn_mfma_f32_16x16x32_f16(sm.w3[7][l3i], C1, a3, 0, 0, 0);
        half8 D0 = act8(a0, a2);
        half8 D1 = act8(a1, a3);

        // ---- layer 4 + store ----
        floatx4 a4 = __builtin_amdgcn_mfma_f32_16x16x32_f16(w4f[0], D0, a4init, 0, 0, 0);
        a4 = __builtin_amdgcn_mfma_f32_16x16x32_f16(w4f[1], D1, a4, 0, 0, 0);
        if (q == 0)
            out[(tile << 4) + m] = act_rev(a4[0]);

        xv = xnext;
        tile = nt;
    }
}

extern "C" void kernel_launch(void* const* d_in, const int* in_sizes, int n_in,
                              void* d_out, int out_size, void* d_ws, size_t ws_size,
                              hipStream_t stream) {
    const float* x  = (const float*)d_in[0];
    const float* W1 = (const float*)d_in[1];
    const float* b1 = (const float*)d_in[2];
    const float* W2 = (const float*)d_in[3];
    const float* b2 = (const float*)d_in[4];
    const float* W3 = (const float*)d_in[5];
    const float* b3 = (const float*)d_in[6];
    const float* W4 = (const float*)d_in[7];
    const float* b4 = (const float*)d_in[8];
    float* out = (float*)d_out;
    const int N = out_size;          // 2097152, divisible by 16

    // R0-best config: 2048 blocks x 8 waves = 16384 waves; 131072 tiles
    // -> 8 tiles/wave. 4 resident 512-thread blocks/CU at 24.6KB LDS each.
    mlp_fused<<<dim3(2048), dim3(512), 0, stream>>>(x, W1, b1, W2, b2, W3, b3, W4, b4, out, N);
}

// Round 6
// 191.798 us; speedup vs baseline: 1.0306x; 1.0306x over previous
//
#include <hip/hip_runtime.h>

typedef _Float16 half8  __attribute__((ext_vector_type(8)));
typedef _Float16 half4v __attribute__((ext_vector_type(4)));
typedef _Float16 half2v __attribute__((ext_vector_type(2)));
typedef float    floatx4 __attribute__((ext_vector_type(4)));
typedef float    float2v __attribute__((ext_vector_type(2)));

static constexpr float INVPI = 0.3183098861837907f;  // weights pre-scaled by 1/pi:
static constexpr float RLOG  = 3.82843f;             // MFMA emits 2*theta in revolutions

// Fused activation via double-angle (R16-verified): h = E + c2*(F + G*c2),
// c2 = cos(2theta), one cos per value.
// Tail in PACKED F16 (v_pk_fma_f16). The f32 v_pk_fma_f32 INLINE-ASM path
// FAILED numerically twice (R17/R18) -- do not retry it. (float2v via
// __builtin_elementwise_fma below is compiler-generated, exact per-lane IEEE,
// and safe whether or not it packs.)
static constexpr double RD = (double)RLOG;
static constexpr double AD = RD*RD/4.0 - RD*RD*RD/16.0;
static constexpr double BD = -RD*RD/4.0 + RD*RD*RD/8.0;
static constexpr double DD = -RD*RD*RD/16.0;
static constexpr float ACT_E = (float)(AD + BD/2.0 + DD/4.0);   //  0.955347
static constexpr float ACT_F = (float)((BD + DD)/2.0);          // -0.078584
static constexpr float ACT_G = (float)(DD/4.0);                 // -0.876763

// R23 (poly, correct theory): 48 wave64 v_cos/tile x ~32cyc = 93% trans-pipe
// saturation was the R0-R4 wall; poly on full-rate VALU removes it.
// R24 (this round): R5's regression was SPILLS, not the poly -- WRITE_SIZE
// 8->19MB, FETCH +4MB, VALUBusy x dur 54->93us of spill code. Cause: (512,8)
// caps the UNIFIED VGPR+AGPR file at 64/wave; ~32 acc regs for MFMA left no
// room for the poly's k/r/u/p transients (4 parallel 6-deep chains).
// Fix: (512,4) -> 128-reg budget, 16 waves/CU. R4 showed extra waves weren't
// what closed the pipe gap, so spending occupancy on registers is the cheap
// side of the trade. Verify via WRITE_SIZE == 8192 KB exactly.
static constexpr double W2D = 39.478417604357434;    // (2*pi)^2
static constexpr float CC1 = (float)(-W2D/2.0);                          // -19.7392088
static constexpr float CC2 = (float)( W2D*W2D/24.0);                     //  64.9393940
static constexpr float CC3 = (float)(-W2D*W2D*W2D/720.0);                // -85.4568172
static constexpr float CC4 = (float)( W2D*W2D*W2D*W2D/40320.0);          //  60.2446398
static constexpr float CC5 = (float)(-W2D*W2D*W2D*W2D*W2D/3628800.0);    // -26.4263128
static constexpr float CC6 = (float)( W2D*W2D*W2D*W2D*W2D*W2D/479001600.0
                                      - 0.4105845);                      //   7.4929525 (minimax tweak)

__device__ __forceinline__ float cos2pi_s(float a) {   // cos(2*pi*a), |a| < 3
    float k = __builtin_rintf(a);                      // v_rndne_f32 (exact)
    float r = a - k;                                   // exact, r in [-0.5, 0.5]
    float u = r * r;                                   // u in [0, 0.25]
    float p = __builtin_fmaf(u, CC6, CC5);
    p = __builtin_fmaf(u, p, CC4);
    p = __builtin_fmaf(u, p, CC3);
    p = __builtin_fmaf(u, p, CC2);
    p = __builtin_fmaf(u, p, CC1);
    p = __builtin_fmaf(u, p, 1.0f);
    return p;
}

__device__ __forceinline__ float2v cos2pi_x2(float2v a) {  // packed-friendly pair form
    float2v k = {__builtin_rintf(a[0]), __builtin_rintf(a[1])};
    float2v r = a - k;
    float2v u = r * r;
    const float2v c6 = {CC6, CC6}, c5 = {CC5, CC5}, c4 = {CC4, CC4};
    const float2v c3 = {CC3, CC3}, c2 = {CC2, CC2}, c1 = {CC1, CC1};
    const float2v one = {1.0f, 1.0f};
    float2v p = __builtin_elementwise_fma(u, c6, c5);
    p = __builtin_elementwise_fma(u, p, c4);
    p = __builtin_elementwise_fma(u, p, c3);
    p = __builtin_elementwise_fma(u, p, c2);
    p = __builtin_elementwise_fma(u, p, c1);
    p = __builtin_elementwise_fma(u, p, one);
    return p;
}

__device__ __forceinline__ float act_rev(float a2) {   // a2 = 2*theta in revs (f32: final output)
    float c = cos2pi_s(a2);
    float t = __builtin_fmaf(ACT_G, c, ACT_F);
    return __builtin_fmaf(c, t, ACT_E);
}

// Two C-frags (tiles t, t+2) -> next-layer B-frag directly.
// Per 8 values: 4x packed poly (no trans!) + 4 cvt_pkrtz + 8 v_pk_fma_f16.
__device__ __forceinline__ half8 act8(floatx4 a, floatx4 b) {
    const half2v Gh = {(_Float16)ACT_G, (_Float16)ACT_G};
    const half2v Fh = {(_Float16)ACT_F, (_Float16)ACT_F};
    const half2v Eh = {(_Float16)ACT_E, (_Float16)ACT_E};
    float2v p0 = cos2pi_x2(float2v{a[0], a[1]});
    float2v p1 = cos2pi_x2(float2v{a[2], a[3]});
    float2v p2 = cos2pi_x2(float2v{b[0], b[1]});
    float2v p3 = cos2pi_x2(float2v{b[2], b[3]});
    half2v c0 = __builtin_bit_cast(half2v, __builtin_amdgcn_cvt_pkrtz(p0[0], p0[1]));
    half2v c1 = __builtin_bit_cast(half2v, __builtin_amdgcn_cvt_pkrtz(p1[0], p1[1]));
    half2v c2 = __builtin_bit_cast(half2v, __builtin_amdgcn_cvt_pkrtz(p2[0], p2[1]));
    half2v c3 = __builtin_bit_cast(half2v, __builtin_amdgcn_cvt_pkrtz(p3[0], p3[1]));
    half2v t0 = __builtin_elementwise_fma(c0, Gh, Fh);
    half2v t1 = __builtin_elementwise_fma(c1, Gh, Fh);
    half2v t2 = __builtin_elementwise_fma(c2, Gh, Fh);
    half2v t3 = __builtin_elementwise_fma(c3, Gh, Fh);
    half2v h0 = __builtin_elementwise_fma(c0, t0, Eh);
    half2v h1 = __builtin_elementwise_fma(c1, t1, Eh);
    half2v h2 = __builtin_elementwise_fma(c2, t2, Eh);
    half2v h3 = __builtin_elementwise_fma(c3, t3, Eh);
    half4v lo = __builtin_shufflevector(h0, h1, 0, 1, 2, 3);
    half4v hi = __builtin_shufflevector(h2, h3, 0, 1, 2, 3);
    return __builtin_shufflevector(lo, hi, 0, 1, 2, 3, 4, 5, 6, 7);
}

// Per-block LDS weight cache (R9/R11-proven). Biases stay in LDS.
struct SMem {
    half8   w2[8][64];   // [(t*2+c)][lane]
    half8   w3[8][64];
    floatx4 b2[4][64];   // [t][lane]
    floatx4 b3[4][64];
};

__global__ __launch_bounds__(512, 4) void mlp_fused(
    const float* __restrict__ x,
    const float* __restrict__ W1, const float* __restrict__ b1,
    const float* __restrict__ W2, const float* __restrict__ b2,
    const float* __restrict__ W3, const float* __restrict__ b3,
    const float* __restrict__ W4, const float* __restrict__ b4,
    float* __restrict__ out, int N)
{
    __shared__ SMem sm;
    const int lane = threadIdx.x & 63;
    const int wib  = threadIdx.x >> 6;   // 0..7
    const int m    = lane & 15;   // sample / C col / A row
    const int q    = lane >> 4;   // quad
    const float s  = INVPI;      // all layers: 1/pi scaling (double-angle form)
    const floatx4 zero4 = {0.0f, 0.0f, 0.0f, 0.0f};

    // ---- in-register persistent frags (small): L1 and L4 ----
    // L1 A-frag (tile t), lanes q==0: [w0h, w0h, w0l, w1h, w1h, w1l, b1h, b1l]
    half8 w1f[4];
    #pragma unroll
    for (int t = 0; t < 4; ++t) {
        half8 v = {};
        if (q == 0) {
            const int n = 16 * t + m;
            float w0 = W1[2*n] * s, w1 = W1[2*n+1] * s, bb = b1[n] * s;
            _Float16 w0h = (_Float16)w0; float w0l = w0 - (float)w0h;
            _Float16 w1h = (_Float16)w1; float w1l = w1 - (float)w1h;
            _Float16 bh  = (_Float16)bb; float bl  = bb - (float)bh;
            v[0] = w0h; v[1] = w0h; v[2] = (_Float16)w0l;
            v[3] = w1h; v[4] = w1h; v[5] = (_Float16)w1l;
            v[6] = bh;  v[7] = (_Float16)bl;
        }
        w1f[t] = v;
    }
    // L4 A-frag: only out-row m==0 real; sigma column permutation
    //   sigma: k-slot (c,q,j) -> neuron (j<4 ? 16c+4q+j : 16(c+2)+4q+j-4)
    half8 w4f[2] = {half8{}, half8{}};
    if (m == 0) {
        #pragma unroll
        for (int c = 0; c < 2; ++c)
            #pragma unroll
            for (int j = 0; j < 8; ++j) {
                int nu = (j < 4) ? (16 * c + 4 * q + j) : (16 * (c + 2) + 4 * q + j - 4);
                w4f[c][j] = (_Float16)(W4[nu] * s);
            }
    }
    floatx4 a4init = zero4;
    if (q == 0) a4init[0] = b4[0] * s;       // C row 0 = (q=0, r=0)

    // ---- wave-split LDS prep (sigma-permuted columns), one barrier ----
    if (wib == 0) {
        #pragma unroll
        for (int t = 0; t < 4; ++t) {
            const float* r2 = W2 + (16 * t + m) * 64;
            #pragma unroll
            for (int c = 0; c < 2; ++c) {
                floatx4 lo2 = *(const floatx4*)(r2 + 16 * c + 4 * q);
                floatx4 hi2 = *(const floatx4*)(r2 + 16 * (c + 2) + 4 * q);
                half8 v2;
                #pragma unroll
                for (int j = 0; j < 4; ++j) {
                    v2[j]     = (_Float16)(lo2[j] * s);
                    v2[4 + j] = (_Float16)(hi2[j] * s);
                }
                sm.w2[t * 2 + c][lane] = v2;
            }
        }
    } else if (wib == 1) {
        #pragma unroll
        for (int t = 0; t < 4; ++t) {
            const float* r3 = W3 + (16 * t + m) * 64;
            #pragma unroll
            for (int c = 0; c < 2; ++c) {
                floatx4 lo3 = *(const floatx4*)(r3 + 16 * c + 4 * q);
                floatx4 hi3 = *(const floatx4*)(r3 + 16 * (c + 2) + 4 * q);
                half8 v3;
                #pragma unroll
                for (int j = 0; j < 4; ++j) {
                    v3[j]     = (_Float16)(lo3[j] * s);
                    v3[4 + j] = (_Float16)(hi3[j] * s);
                }
                sm.w3[t * 2 + c][lane] = v3;
            }
        }
    } else if (wib == 2) {
        #pragma unroll
        for (int t = 0; t < 4; ++t) {
            sm.b2[t][lane] = *(const floatx4*)(b2 + 16 * t + 4 * q) * s;
            sm.b3[t][lane] = *(const floatx4*)(b3 + 16 * t + 4 * q) * s;
        }
    }
    __syncthreads();

    const int ntiles = N >> 4;
    const int nwaves = (gridDim.x * blockDim.x) >> 6;
    const int gwave  = (int)(blockIdx.x * blockDim.x + threadIdx.x) >> 6;
    const float2* __restrict__ x2 = (const float2*)x;

    int tile = gwave;
    float2 xv = x2[(tile << 4) + m];          // 1-ahead x prefetch
    while (tile < ntiles) {
        const int nt = tile + nwaves;
        float2 xnext;
        if (nt < ntiles) xnext = x2[(nt << 4) + m];

        // L1 B-frag (lanes q==0): [xh, xl, xh, yh, yl, yh, 1, 1]
        half8 xa = {};
        if (q == 0) {
            _Float16 xh = (_Float16)xv.x; float xl = xv.x - (float)xh;
            _Float16 yh = (_Float16)xv.y; float yl = xv.y - (float)yh;
            xa[0] = xh; xa[1] = (_Float16)xl; xa[2] = xh;
            xa[3] = yh; xa[4] = (_Float16)yl; xa[5] = yh;
            xa[6] = (_Float16)1.0f; xa[7] = (_Float16)1.0f;
        }

        // ---- layer 1 (in-register frags) ----
        floatx4 a0 = __builtin_amdgcn_mfma_f32_16x16x32_f16(w1f[0], xa, zero4, 0, 0, 0);
        floatx4 a1 = __builtin_amdgcn_mfma_f32_16x16x32_f16(w1f[1], xa, zero4, 0, 0, 0);
        floatx4 a2 = __builtin_amdgcn_mfma_f32_16x16x32_f16(w1f[2], xa, zero4, 0, 0, 0);
        floatx4 a3 = __builtin_amdgcn_mfma_f32_16x16x32_f16(w1f[3], xa, zero4, 0, 0, 0);
        half8 B0 = act8(a0, a2);
        half8 B1 = act8(a1, a3);

        // Opaque zero per layer: defeats LICM (else the LDS reads hoist back
        // into live regs and spill) AND staggers reads so peak staging
        // is one layer's worth.
        int z2 = 0; asm volatile("" : "+v"(z2));
        const int l2i = lane + z2;
        a0 = __builtin_amdgcn_mfma_f32_16x16x32_f16(sm.w2[0][l2i], B0, sm.b2[0][l2i], 0, 0, 0);
        a1 = __builtin_amdgcn_mfma_f32_16x16x32_f16(sm.w2[2][l2i], B0, sm.b2[1][l2i], 0, 0, 0);
        a2 = __builtin_amdgcn_mfma_f32_16x16x32_f16(sm.w2[4][l2i], B0, sm.b2[2][l2i], 0, 0, 0);
        a3 = __builtin_amdgcn_mfma_f32_16x16x32_f16(sm.w2[6][l2i], B0, sm.b2[3][l2i], 0, 0, 0);
        a0 = __builtin_amdgcn_mfma_f32_16x16x32_f16(sm.w2[1][l2i], B1, a0, 0, 0, 0);
        a1 = __builtin_amdgcn_mfma_f32_16x16x32_f16(sm.w2[3][l2i], B1, a1, 0, 0, 0);
        a2 = __builtin_amdgcn_mfma_f32_16x16x32_f16(sm.w2[5][l2i], B1, a2, 0, 0, 0);
        a3 = __builtin_amdgcn_mfma_f32_16x16x32_f16(sm.w2[7][l2i], B1, a3, 0, 0, 0);
        half8 C0 = act8(a0, a2);
        half8 C1 = act8(a1, a3);

        int z3 = 0; asm volatile("" : "+v"(z3));
        const int l3i = lane + z3;
        a0 = __builtin_amdgcn_mfma_f32_16x16x32_f16(sm.w3[0][l3i], C0, sm.b3[0][l3i], 0, 0, 0);
        a1 = __builtin_amdgcn_mfma_f32_16x16x32_f16(sm.w3[2][l3i], C0, sm.b3[1][l3i], 0, 0, 0);
        a2 = __builtin_amdgcn_mfma_f32_16x16x32_f16(sm.w3[4][l3i], C0, sm.b3[2][l3i], 0, 0, 0);
        a3 = __builtin_amdgcn_mfma_f32_16x16x32_f16(sm.w3[6][l3i], C0, sm.b3[3][l3i], 0, 0, 0);
        a0 = __builtin_amdgcn_mfma_f32_16x16x32_f16(sm.w3[1][l3i], C1, a0, 0, 0, 0);
        a1 = __builtin_amdgcn_mfma_f32_16x16x32_f16(sm.w3[3][l3i], C1, a1, 0, 0, 0);
        a2 = __builtin_amdgcn_mfma_f32_16x16x32_f16(sm.w3[5][l3i], C1, a2, 0, 0, 0);
        a3 = __builtin_amdgcn_mfma_f32_16x16x32_f16(sm.w3[7][l3i], C1, a3, 0, 0, 0);
        half8 D0 = act8(a0, a2);
        half8 D1 = act8(a1, a3);

        // ---- layer 4 + store ----
        floatx4 a4 = __builtin_amdgcn_mfma_f32_16x16x32_f16(w4f[0], D0, a4init, 0, 0, 0);
        a4 = __builtin_amdgcn_mfma_f32_16x16x32_f16(w4f[1], D1, a4, 0, 0, 0);
        if (q == 0)
            out[(tile << 4) + m] = act_rev(a4[0]);

        xv = xnext;
        tile = nt;
    }
}

extern "C" void kernel_launch(void* const* d_in, const int* in_sizes, int n_in,
                              void* d_out, int out_size, void* d_ws, size_t ws_size,
                              hipStream_t stream) {
    const float* x  = (const float*)d_in[0];
    const float* W1 = (const float*)d_in[1];
    const float* b1 = (const float*)d_in[2];
    const float* W2 = (const float*)d_in[3];
    const float* b2 = (const float*)d_in[4];
    const float* W3 = (const float*)d_in[5];
    const float* b3 = (const float*)d_in[6];
    const float* W4 = (const float*)d_in[7];
    const float* b4 = (const float*)d_in[8];
    float* out = (float*)d_out;
    const int N = out_size;          // 2097152, divisible by 16

    // R24 config: 2048 blocks x 8 waves = 16384 waves; 131072 tiles
    // -> 8 tiles/wave. (512,4): 128-reg unified budget, 2 resident
    // 512-thread blocks/CU (16 waves) at 24.6KB LDS each.
    mlp_fused<<<dim3(2048), dim3(512), 0, stream>>>(x, W1, b1, W2, b2, W3, b3, W4, b4, out, N);
}

// Round 7
// 161.198 us; speedup vs baseline: 1.2262x; 1.1898x over previous
//
#include <hip/hip_runtime.h>

typedef _Float16 half8  __attribute__((ext_vector_type(8)));
typedef _Float16 half4v __attribute__((ext_vector_type(4)));
typedef _Float16 half2v __attribute__((ext_vector_type(2)));
typedef float    floatx4 __attribute__((ext_vector_type(4)));
typedef float    float2v __attribute__((ext_vector_type(2)));

static constexpr float INVPI = 0.3183098861837907f;  // weights pre-scaled by 1/pi:
static constexpr float RLOG  = 3.82843f;             // MFMA emits 2*theta in revolutions

// Fused activation via double-angle (R16-verified): h = E + c2*(F + G*c2),
// c2 = cos(2theta), one cos per value.
// Tail in PACKED F16 (v_pk_fma_f16). The f32 v_pk_fma_f32 INLINE-ASM path
// FAILED numerically twice (R17/R18) -- do not retry it.
static constexpr double RD = (double)RLOG;
static constexpr double AD = RD*RD/4.0 - RD*RD*RD/16.0;
static constexpr double BD = -RD*RD/4.0 + RD*RD*RD/8.0;
static constexpr double DD = -RD*RD*RD/16.0;
static constexpr float ACT_E = (float)(AD + BD/2.0 + DD/4.0);   //  0.955347
static constexpr float ACT_F = (float)((BD + DD)/2.0);          // -0.078584
static constexpr float ACT_G = (float)(DD/4.0);                 // -0.876763

// R25 pipe-balance model (from R0-R4 trans-only and R5-R6 poly-only bench pairs):
//   v_cos : ~2 issue-cyc + 32 cyc TRANS-unit occupancy per wave64 value
//   poly  : ~18 issue-cyc on full-rate VALU (compiler scalarizes float2v; the
//           packed-asm route is banned), zero trans
//   trans-only: trans 1536/1612 cyc/tile = 95% saturated (the 86us wall)
//   poly-only:  issue 1743 cyc/tile (the 139us wall)
// HYBRID f=0.25 (2 of 8 values per act8 on poly): issue ~1222, trans ~1152
// -> both pipes ~75-80%, floor ~64us. Poly kept deg-6 (bit-identical absmax
// across R5/R6 proves numerics). Config back to best-measured (512,8)/2048.
static constexpr double W2D = 39.478417604357434;    // (2*pi)^2
static constexpr float CC1 = (float)(-W2D/2.0);                          // -19.7392088
static constexpr float CC2 = (float)( W2D*W2D/24.0);                     //  64.9393940
static constexpr float CC3 = (float)(-W2D*W2D*W2D/720.0);                // -85.4568172
static constexpr float CC4 = (float)( W2D*W2D*W2D*W2D/40320.0);          //  60.2446398
static constexpr float CC5 = (float)(-W2D*W2D*W2D*W2D*W2D/3628800.0);    // -26.4263128
static constexpr float CC6 = (float)( W2D*W2D*W2D*W2D*W2D*W2D/479001600.0
                                      - 0.4105845);                      //   7.4929525 (minimax tweak)

__device__ __forceinline__ float2v cos2pi_x2(float2v a) {  // VALU poly pair, |a|<3
    float2v k = {__builtin_rintf(a[0]), __builtin_rintf(a[1])};
    float2v r = a - k;                                     // exact, r in [-0.5,0.5]
    float2v u = r * r;
    const float2v c6 = {CC6, CC6}, c5 = {CC5, CC5}, c4 = {CC4, CC4};
    const float2v c3 = {CC3, CC3}, c2 = {CC2, CC2}, c1 = {CC1, CC1};
    const float2v one = {1.0f, 1.0f};
    float2v p = __builtin_elementwise_fma(u, c6, c5);
    p = __builtin_elementwise_fma(u, p, c4);
    p = __builtin_elementwise_fma(u, p, c3);
    p = __builtin_elementwise_fma(u, p, c2);
    p = __builtin_elementwise_fma(u, p, c1);
    p = __builtin_elementwise_fma(u, p, one);
    return p;
}

__device__ __forceinline__ float act_rev(float a2) {   // final output: 1 value/tile, trans is free here
    float c = __builtin_amdgcn_cosf(a2);
    float t = __builtin_fmaf(ACT_G, c, ACT_F);
    return __builtin_fmaf(c, t, ACT_E);
}

// HYBRID act8: values a[0],a[1] via VALU poly; a[2],a[3],b[0..3] via trans v_cos.
// Per 8 values: 1 packed-pair poly (+~9 ops) + 6 v_cos + 4 cvt_pkrtz + 8 v_pk_fma_f16.
__device__ __forceinline__ half8 act8(floatx4 a, floatx4 b) {
    const half2v Gh = {(_Float16)ACT_G, (_Float16)ACT_G};
    const half2v Fh = {(_Float16)ACT_F, (_Float16)ACT_F};
    const half2v Eh = {(_Float16)ACT_E, (_Float16)ACT_E};
    float2v p0 = cos2pi_x2(float2v{a[0], a[1]});           // VALU pipe
    half2v c0 = __builtin_bit_cast(half2v, __builtin_amdgcn_cvt_pkrtz(p0[0], p0[1]));
    half2v c1 = __builtin_bit_cast(half2v, __builtin_amdgcn_cvt_pkrtz(
                    __builtin_amdgcn_cosf(a[2]), __builtin_amdgcn_cosf(a[3])));
    half2v c2 = __builtin_bit_cast(half2v, __builtin_amdgcn_cvt_pkrtz(
                    __builtin_amdgcn_cosf(b[0]), __builtin_amdgcn_cosf(b[1])));
    half2v c3 = __builtin_bit_cast(half2v, __builtin_amdgcn_cvt_pkrtz(
                    __builtin_amdgcn_cosf(b[2]), __builtin_amdgcn_cosf(b[3])));
    half2v t0 = __builtin_elementwise_fma(c0, Gh, Fh);
    half2v t1 = __builtin_elementwise_fma(c1, Gh, Fh);
    half2v t2 = __builtin_elementwise_fma(c2, Gh, Fh);
    half2v t3 = __builtin_elementwise_fma(c3, Gh, Fh);
    half2v h0 = __builtin_elementwise_fma(c0, t0, Eh);
    half2v h1 = __builtin_elementwise_fma(c1, t1, Eh);
    half2v h2 = __builtin_elementwise_fma(c2, t2, Eh);
    half2v h3 = __builtin_elementwise_fma(c3, t3, Eh);
    half4v lo = __builtin_shufflevector(h0, h1, 0, 1, 2, 3);
    half4v hi = __builtin_shufflevector(h2, h3, 0, 1, 2, 3);
    return __builtin_shufflevector(lo, hi, 0, 1, 2, 3, 4, 5, 6, 7);
}

// Per-block LDS weight cache (R9/R11-proven; biases stay in LDS -- R12 showed
// biases-in-regs spill at the (512,8) 64-reg cap). R0/R11/R16 config exactly.
struct SMem {
    half8   w2[8][64];   // [(t*2+c)][lane]
    half8   w3[8][64];
    floatx4 b2[4][64];   // [t][lane]
    floatx4 b3[4][64];
};

__global__ __launch_bounds__(512, 8) void mlp_fused(
    const float* __restrict__ x,
    const float* __restrict__ W1, const float* __restrict__ b1,
    const float* __restrict__ W2, const float* __restrict__ b2,
    const float* __restrict__ W3, const float* __restrict__ b3,
    const float* __restrict__ W4, const float* __restrict__ b4,
    float* __restrict__ out, int N)
{
    __shared__ SMem sm;
    const int lane = threadIdx.x & 63;
    const int wib  = threadIdx.x >> 6;   // 0..7
    const int m    = lane & 15;   // sample / C col / A row
    const int q    = lane >> 4;   // quad
    const float s  = INVPI;      // all layers: 1/pi scaling (double-angle form)
    const floatx4 zero4 = {0.0f, 0.0f, 0.0f, 0.0f};

    // ---- in-register persistent frags (small): L1 and L4 ----
    // L1 A-frag (tile t), lanes q==0: [w0h, w0h, w0l, w1h, w1h, w1l, b1h, b1l]
    half8 w1f[4];
    #pragma unroll
    for (int t = 0; t < 4; ++t) {
        half8 v = {};
        if (q == 0) {
            const int n = 16 * t + m;
            float w0 = W1[2*n] * s, w1 = W1[2*n+1] * s, bb = b1[n] * s;
            _Float16 w0h = (_Float16)w0; float w0l = w0 - (float)w0h;
            _Float16 w1h = (_Float16)w1; float w1l = w1 - (float)w1h;
            _Float16 bh  = (_Float16)bb; float bl  = bb - (float)bh;
            v[0] = w0h; v[1] = w0h; v[2] = (_Float16)w0l;
            v[3] = w1h; v[4] = w1h; v[5] = (_Float16)w1l;
            v[6] = bh;  v[7] = (_Float16)bl;
        }
        w1f[t] = v;
    }
    // L4 A-frag: only out-row m==0 real; sigma column permutation
    //   sigma: k-slot (c,q,j) -> neuron (j<4 ? 16c+4q+j : 16(c+2)+4q+j-4)
    half8 w4f[2] = {half8{}, half8{}};
    if (m == 0) {
        #pragma unroll
        for (int c = 0; c < 2; ++c)
            #pragma unroll
            for (int j = 0; j < 8; ++j) {
                int nu = (j < 4) ? (16 * c + 4 * q + j) : (16 * (c + 2) + 4 * q + j - 4);
                w4f[c][j] = (_Float16)(W4[nu] * s);
            }
    }
    floatx4 a4init = zero4;
    if (q == 0) a4init[0] = b4[0] * s;       // C row 0 = (q=0, r=0)

    // ---- wave-split LDS prep (sigma-permuted columns), one barrier ----
    if (wib == 0) {
        #pragma unroll
        for (int t = 0; t < 4; ++t) {
            const float* r2 = W2 + (16 * t + m) * 64;
            #pragma unroll
            for (int c = 0; c < 2; ++c) {
                floatx4 lo2 = *(const floatx4*)(r2 + 16 * c + 4 * q);
                floatx4 hi2 = *(const floatx4*)(r2 + 16 * (c + 2) + 4 * q);
                half8 v2;
                #pragma unroll
                for (int j = 0; j < 4; ++j) {
                    v2[j]     = (_Float16)(lo2[j] * s);
                    v2[4 + j] = (_Float16)(hi2[j] * s);
                }
                sm.w2[t * 2 + c][lane] = v2;
            }
        }
    } else if (wib == 1) {
        #pragma unroll
        for (int t = 0; t < 4; ++t) {
            const float* r3 = W3 + (16 * t + m) * 64;
            #pragma unroll
            for (int c = 0; c < 2; ++c) {
                floatx4 lo3 = *(const floatx4*)(r3 + 16 * c + 4 * q);
                floatx4 hi3 = *(const floatx4*)(r3 + 16 * (c + 2) + 4 * q);
                half8 v3;
                #pragma unroll
                for (int j = 0; j < 4; ++j) {
                    v3[j]     = (_Float16)(lo3[j] * s);
                    v3[4 + j] = (_Float16)(hi3[j] * s);
                }
                sm.w3[t * 2 + c][lane] = v3;
            }
        }
    } else if (wib == 2) {
        #pragma unroll
        for (int t = 0; t < 4; ++t) {
            sm.b2[t][lane] = *(const floatx4*)(b2 + 16 * t + 4 * q) * s;
            sm.b3[t][lane] = *(const floatx4*)(b3 + 16 * t + 4 * q) * s;
        }
    }
    __syncthreads();

    const int ntiles = N >> 4;
    const int nwaves = (gridDim.x * blockDim.x) >> 6;
    const int gwave  = (int)(blockIdx.x * blockDim.x + threadIdx.x) >> 6;
    const float2* __restrict__ x2 = (const float2*)x;

    int tile = gwave;
    float2 xv = x2[(tile << 4) + m];          // 1-ahead x prefetch
    while (tile < ntiles) {
        const int nt = tile + nwaves;
        float2 xnext;
        if (nt < ntiles) xnext = x2[(nt << 4) + m];

        // L1 B-frag (lanes q==0): [xh, xl, xh, yh, yl, yh, 1, 1]
        half8 xa = {};
        if (q == 0) {
            _Float16 xh = (_Float16)xv.x; float xl = xv.x - (float)xh;
            _Float16 yh = (_Float16)xv.y; float yl = xv.y - (float)yh;
            xa[0] = xh; xa[1] = (_Float16)xl; xa[2] = xh;
            xa[3] = yh; xa[4] = (_Float16)yl; xa[5] = yh;
            xa[6] = (_Float16)1.0f; xa[7] = (_Float16)1.0f;
        }

        // ---- layer 1 (in-register frags) ----
        floatx4 a0 = __builtin_amdgcn_mfma_f32_16x16x32_f16(w1f[0], xa, zero4, 0, 0, 0);
        floatx4 a1 = __builtin_amdgcn_mfma_f32_16x16x32_f16(w1f[1], xa, zero4, 0, 0, 0);
        floatx4 a2 = __builtin_amdgcn_mfma_f32_16x16x32_f16(w1f[2], xa, zero4, 0, 0, 0);
        floatx4 a3 = __builtin_amdgcn_mfma_f32_16x16x32_f16(w1f[3], xa, zero4, 0, 0, 0);
        half8 B0 = act8(a0, a2);
        half8 B1 = act8(a1, a3);

        // Opaque zero per layer: defeats LICM (else the LDS reads hoist back
        // into live regs and spill) AND staggers reads so peak staging
        // is one layer's worth.
        int z2 = 0; asm volatile("" : "+v"(z2));
        const int l2i = lane + z2;
        a0 = __builtin_amdgcn_mfma_f32_16x16x32_f16(sm.w2[0][l2i], B0, sm.b2[0][l2i], 0, 0, 0);
        a1 = __builtin_amdgcn_mfma_f32_16x16x32_f16(sm.w2[2][l2i], B0, sm.b2[1][l2i], 0, 0, 0);
        a2 = __builtin_amdgcn_mfma_f32_16x16x32_f16(sm.w2[4][l2i], B0, sm.b2[2][l2i], 0, 0, 0);
        a3 = __builtin_amdgcn_mfma_f32_16x16x32_f16(sm.w2[6][l2i], B0, sm.b2[3][l2i], 0, 0, 0);
        a0 = __builtin_amdgcn_mfma_f32_16x16x32_f16(sm.w2[1][l2i], B1, a0, 0, 0, 0);
        a1 = __builtin_amdgcn_mfma_f32_16x16x32_f16(sm.w2[3][l2i], B1, a1, 0, 0, 0);
        a2 = __builtin_amdgcn_mfma_f32_16x16x32_f16(sm.w2[5][l2i], B1, a2, 0, 0, 0);
        a3 = __builtin_amdgcn_mfma_f32_16x16x32_f16(sm.w2[7][l2i], B1, a3, 0, 0, 0);
        half8 C0 = act8(a0, a2);
        half8 C1 = act8(a1, a3);

        int z3 = 0; asm volatile("" : "+v"(z3));
        const int l3i = lane + z3;
        a0 = __builtin_amdgcn_mfma_f32_16x16x32_f16(sm.w3[0][l3i], C0, sm.b3[0][l3i], 0, 0, 0);
        a1 = __builtin_amdgcn_mfma_f32_16x16x32_f16(sm.w3[2][l3i], C0, sm.b3[1][l3i], 0, 0, 0);
        a2 = __builtin_amdgcn_mfma_f32_16x16x32_f16(sm.w3[4][l3i], C0, sm.b3[2][l3i], 0, 0, 0);
        a3 = __builtin_amdgcn_mfma_f32_16x16x32_f16(sm.w3[6][l3i], C0, sm.b3[3][l3i], 0, 0, 0);
        a0 = __builtin_amdgcn_mfma_f32_16x16x32_f16(sm.w3[1][l3i], C1, a0, 0, 0, 0);
        a1 = __builtin_amdgcn_mfma_f32_16x16x32_f16(sm.w3[3][l3i], C1, a1, 0, 0, 0);
        a2 = __builtin_amdgcn_mfma_f32_16x16x32_f16(sm.w3[5][l3i], C1, a2, 0, 0, 0);
        a3 = __builtin_amdgcn_mfma_f32_16x16x32_f16(sm.w3[7][l3i], C1, a3, 0, 0, 0);
        half8 D0 = act8(a0, a2);
        half8 D1 = act8(a1, a3);

        // ---- layer 4 + store ----
        floatx4 a4 = __builtin_amdgcn_mfma_f32_16x16x32_f16(w4f[0], D0, a4init, 0, 0, 0);
        a4 = __builtin_amdgcn_mfma_f32_16x16x32_f16(w4f[1], D1, a4, 0, 0, 0);
        if (q == 0)
            out[(tile << 4) + m] = act_rev(a4[0]);

        xv = xnext;
        tile = nt;
    }
}

extern "C" void kernel_launch(void* const* d_in, const int* in_sizes, int n_in,
                              void* d_out, int out_size, void* d_ws, size_t ws_size,
                              hipStream_t stream) {
    const float* x  = (const float*)d_in[0];
    const float* W1 = (const float*)d_in[1];
    const float* b1 = (const float*)d_in[2];
    const float* W2 = (const float*)d_in[3];
    const float* b2 = (const float*)d_in[4];
    const float* W3 = (const float*)d_in[5];
    const float* b3 = (const float*)d_in[6];
    const float* W4 = (const float*)d_in[7];
    const float* b4 = (const float*)d_in[8];
    float* out = (float*)d_out;
    const int N = out_size;          // 2097152, divisible by 16

    // R25 config (= R0 best-measured): 2048 blocks x 8 waves = 16384 waves;
    // 131072 tiles -> 8 tiles/wave. 4 resident 512-thread blocks/CU.
    mlp_fused<<<dim3(2048), dim3(512), 0, stream>>>(x, W1, b1, W2, b2, W3, b3, W4, b4, out, N);
}